// Round 9
// baseline (1011.307 us; speedup 1.0000x reference)
//
#include <hip/hip_runtime.h>
#include <hip/hip_bf16.h>
#include <hip/hip_cooperative_groups.h>

namespace cg = cooperative_groups;

// GCN: 3x GraphConv(sum-agg) + ELU, mean-pool, linear head, log_softmax.
// N=50000, E=400000, G=64, D_IN=200, D_HID=32. fp32 inputs/outputs.
// R9: cooperative single-kernel (R8 idea) but FAIL-SAFE: occupancy-queried
// grid size, grid-stride phases, and a 12-launch fallback path (same device
// phase functions) if hipLaunchCooperativeKernel returns an error. R8 failed
// because the coop launch was rejected (output never written) and there was
// no fallback / error check.

#define D_IN 200
#define N_GRAPHS 64

#define KP 232                 // padded K stride for bf16 Wt
#define KB 7                   // 7 k-blocks of 32
#define WT_ELEMS (64 * KP)     // 14848

#define NT 256
#define NSCB 196               // scan tiles: 196*256 = 50176 >= N

typedef __attribute__((ext_vector_type(8))) short bf16x8;
typedef __attribute__((ext_vector_type(4))) float f32x4;

struct Params {
    const float* x; const int* src; const int* dst; const int* batch;
    const float* W1r; const float* W1l; const float* b1;
    const float* W2r; const float* W2l; const float* b2;
    const float* W3r; const float* W3l; const float* b3;
    const float* Wlin; const float* blin;
    float* out;
    int N; int E;
    int* cnt; int* row_ptr; int* cursor; int* colIdx; int* partial; int* excl;
    __hip_bfloat16* Wt;
    float* yrA; float* ylA; float* yrB; float* ylB; float* hA;
};

__device__ __forceinline__ float4 elu4(float4 v) {
    float4 o;
    o.x = (v.x > 0.f) ? v.x : expm1f(v.x);
    o.y = (v.y > 0.f) ? v.y : expm1f(v.y);
    o.z = (v.z > 0.f) ? v.z : expm1f(v.z);
    o.w = (v.w > 0.f) ? v.w : expm1f(v.w);
    return o;
}

// ---- ph0: zero cnt + pack [W1r|W1l] -> bf16 Wt[64][KP] ----
__device__ void ph_prep(const Params& P, int gtid, int gs) {
    for (int i = gtid; i < P.N + WT_ELEMS; i += gs) {
        if (i < P.N) P.cnt[i] = 0;
        else {
            int idx = i - P.N;
            int n = idx / KP, k = idx % KP;
            float v = 0.f;
            if (k < D_IN) v = (n < 32) ? P.W1r[k * 32 + n] : P.W1l[k * 32 + (n - 32)];
            P.Wt[idx] = __float2bfloat16(v);
        }
    }
}

// ---- ph1: count in-degrees ----
__device__ void ph_count(const Params& P, int gtid, int gs) {
    for (int e = gtid; e < P.E; e += gs) atomicAdd(&P.cnt[P.dst[e]], 1);
}

// ---- ph2: per-tile local scan -> excl[idx], partial[tile] ----
__device__ void ph_scanA(const Params& P, int bid, int nb, int tid, int* scanS) {
    for (int tile = bid; tile < NSCB; tile += nb) {
        __syncthreads();
        int idx = tile * NT + tid;
        int v = (idx < P.N) ? P.cnt[idx] : 0;
        scanS[tid] = v;
        __syncthreads();
        for (int off = 1; off < NT; off <<= 1) {
            int u = (tid >= off) ? scanS[tid - off] : 0;
            __syncthreads();
            scanS[tid] += u;
            __syncthreads();
        }
        int incl = scanS[tid];
        if (idx < P.N) P.excl[idx] = incl - v;
        if (tid == NT - 1) P.partial[tile] = incl;
    }
}

// ---- ph3: block 0 exclusive-scans the NSCB partials ----
__device__ void ph_scanB(const Params& P, int bid, int tid, int* scanS) {
    if (bid != 0) return;
    int v = (tid < NSCB) ? P.partial[tid] : 0;
    scanS[tid] = v;
    __syncthreads();
    for (int off = 1; off < NT; off <<= 1) {
        int u = (tid >= off) ? scanS[tid - off] : 0;
        __syncthreads();
        scanS[tid] += u;
        __syncthreads();
    }
    if (tid < NSCB) P.partial[tid] = scanS[tid] - v;
}

// ---- ph4: row_ptr / cursor ----
__device__ void ph_rowptr(const Params& P, int gtid, int gs) {
    for (int idx = gtid; idx < P.N; idx += gs) {
        int rp = P.partial[idx >> 8] + P.excl[idx];
        P.row_ptr[idx] = rp;
        P.cursor[idx] = rp;
        if (idx == P.N - 1) P.row_ptr[P.N] = rp + P.cnt[idx];
    }
}

// ---- ph5a: fill CSR ----
__device__ void ph_fill(const Params& P, int gtid, int gs) {
    for (int e = gtid; e < P.E; e += gs) {
        int p = atomicAdd(&P.cursor[P.dst[e]], 1);
        P.colIdx[p] = P.src[e];
    }
}

// ---- ph5b: layer-1 MFMA gemm, LDS-free (R7 body, tile-strided) ----
__device__ void ph_gemm1(const Params& P, int bid, int nb, int tid) {
    int lane = tid & 63, wv = tid >> 6;
    int l15 = lane & 15, q = lane >> 4;
    int N = P.N;
    int ntile = (N + 63) >> 6;
    for (int tile = bid; tile < ntile; tile += nb) {
        long base = (long)tile * 64;
        long row = base + wv * 16 + l15;
        long rowc = (row < (long)N) ? row : (long)(N - 1);
        const float* xr = P.x + rowc * D_IN;
        bf16x8 a[KB];
#pragma unroll
        for (int kb = 0; kb < KB; ++kb) {
            int k0 = kb * 32 + q * 8;
            union { __hip_bfloat16 h[8]; bf16x8 v; } u;
            if (k0 + 8 <= D_IN) {
                float4 v0 = *(const float4*)(xr + k0);
                float4 v1 = *(const float4*)(xr + k0 + 4);
                u.h[0] = __float2bfloat16(v0.x); u.h[1] = __float2bfloat16(v0.y);
                u.h[2] = __float2bfloat16(v0.z); u.h[3] = __float2bfloat16(v0.w);
                u.h[4] = __float2bfloat16(v1.x); u.h[5] = __float2bfloat16(v1.y);
                u.h[6] = __float2bfloat16(v1.z); u.h[7] = __float2bfloat16(v1.w);
            } else {
#pragma unroll
                for (int j = 0; j < 8; ++j) {
                    int k = k0 + j;
                    u.h[j] = __float2bfloat16(k < D_IN ? xr[k] : 0.f);
                }
            }
            a[kb] = u.v;
        }
#pragma unroll
        for (int ns = 0; ns < 4; ++ns) {
            f32x4 acc = {0.f, 0.f, 0.f, 0.f};
#pragma unroll
            for (int kb = 0; kb < KB; ++kb) {
                bf16x8 bfrag = *(const bf16x8*)(const void*)
                    (P.Wt + (ns * 16 + l15) * KP + kb * 32 + q * 8);
                acc = __builtin_amdgcn_mfma_f32_16x16x32_bf16(a[kb], bfrag, acc, 0, 0, 0);
            }
            int col = ns * 16 + l15;
            float* Y = (col < 32) ? P.yrA : P.ylA;
            int cc = col & 31;
#pragma unroll
            for (int r = 0; r < 4; ++r) {
                long node = base + wv * 16 + q * 4 + r;
                if (node < N) Y[node * 32 + cc] = acc[r];
            }
        }
    }
}

// ---- agg (CSR pull) + bias + root + ELU; unroll-8 masked (R7 body) ----
__device__ void ph_agg(const float4* __restrict__ yin_r, const float4* __restrict__ yin_l,
                       const int* __restrict__ row_ptr, const int* __restrict__ colIdx,
                       const float* __restrict__ b, float4* __restrict__ hout,
                       int N, int bid, int nb, int tid) {
    int f4 = tid & 7;
    int ntile = (N + 31) >> 5;
    float4 b4 = ((const float4*)b)[f4];
    for (int tile = bid; tile < ntile; tile += nb) {
        int node = tile * 32 + (tid >> 3);
        if (node >= N) continue;
        int s = row_ptr[node], e = row_ptr[node + 1];
        float4 rv = yin_l[(long)node * 8 + f4];
        float ax = 0.f, ay = 0.f, az = 0.f, aw = 0.f;
        for (int p = s; p < e; p += 8) {
            int jj[8]; float m[8];
#pragma unroll
            for (int i = 0; i < 8; ++i) {
                int pi = p + i;
                m[i] = (pi < e) ? 1.f : 0.f;
                pi = (pi < e) ? pi : (e - 1);
                jj[i] = colIdx[pi];
            }
            float4 v[8];
#pragma unroll
            for (int i = 0; i < 8; ++i) v[i] = yin_r[(long)jj[i] * 8 + f4];
#pragma unroll
            for (int i = 0; i < 8; ++i) {
                ax = fmaf(v[i].x, m[i], ax);
                ay = fmaf(v[i].y, m[i], ay);
                az = fmaf(v[i].z, m[i], az);
                aw = fmaf(v[i].w, m[i], aw);
            }
        }
        hout[(long)node * 8 + f4] = elu4(make_float4(ax + b4.x + rv.x, ay + b4.y + rv.y,
                                                     az + b4.z + rv.z, aw + b4.w + rv.w));
    }
}

// ---- fp32 K=32 gemm, LDS-staged (R7 body) ----
__device__ void ph_gemm32(const float* __restrict__ X, const float* __restrict__ Wr,
                          const float* __restrict__ Wl, float* __restrict__ yr,
                          float* __restrict__ yl, int N, int bid, int nb, int tid,
                          float4* xs) {
    int ntile = (N + 31) >> 5;
    const float4* X4 = (const float4*)X;
    long total4 = (long)N * 8;
    for (int tile = bid; tile < ntile; tile += nb) {
        long base = (long)tile * 32;
        __syncthreads();
        long g0 = base * 8;
        for (int i = tid; i < 32 * 8; i += NT) {
            long gi = g0 + i;
            xs[i] = (gi < total4) ? X4[gi] : make_float4(0.f, 0.f, 0.f, 0.f);
        }
        __syncthreads();
        int c = tid & 31;
        int nb2 = (tid >> 5) * 4;
        float accr[4] = {0.f, 0.f, 0.f, 0.f};
        float accl[4] = {0.f, 0.f, 0.f, 0.f};
        for (int k4 = 0; k4 < 8; ++k4) {
            float wr[4], wl[4];
#pragma unroll
            for (int qq = 0; qq < 4; ++qq) {
                wr[qq] = Wr[(k4 * 4 + qq) * 32 + c];
                wl[qq] = Wl[(k4 * 4 + qq) * 32 + c];
            }
#pragma unroll
            for (int i = 0; i < 4; ++i) {
                float4 xv = xs[(nb2 + i) * 8 + k4];
                accr[i] = fmaf(xv.x, wr[0], accr[i]); accr[i] = fmaf(xv.y, wr[1], accr[i]);
                accr[i] = fmaf(xv.z, wr[2], accr[i]); accr[i] = fmaf(xv.w, wr[3], accr[i]);
                accl[i] = fmaf(xv.x, wl[0], accl[i]); accl[i] = fmaf(xv.y, wl[1], accl[i]);
                accl[i] = fmaf(xv.z, wl[2], accl[i]); accl[i] = fmaf(xv.w, wl[3], accl[i]);
            }
        }
#pragma unroll
        for (int i = 0; i < 4; ++i) {
            long node = base + nb2 + i;
            if (node < N) {
                yr[node * 32 + c] = accr[i];
                yl[node * 32 + c] = accl[i];
            }
        }
    }
}

// ---- pool + head + log_softmax (blocks 0..63) ----
__device__ void ph_pool(const Params& P, int bid, int tid, float4* redS, float* poolS) {
    if (bid >= N_GRAPHS) return;
    int N = P.N;
    const float4* h4 = (const float4*)P.hA;
    int g = bid;
    int lo = 0, hi = N;
    while (lo < hi) { int mid = (lo + hi) >> 1; if (P.batch[mid] < g) lo = mid + 1; else hi = mid; }
    int start = lo;
    hi = N;
    while (lo < hi) { int mid = (lo + hi) >> 1; if (P.batch[mid] < g + 1) lo = mid + 1; else hi = mid; }
    int end = lo;

    int f4 = tid & 7, r = tid >> 3;
    float4 acc = make_float4(0.f, 0.f, 0.f, 0.f);
    for (int i = start + r; i < end; i += 32) {
        float4 v = h4[(long)i * 8 + f4];
        acc.x += v.x; acc.y += v.y; acc.z += v.z; acc.w += v.w;
    }
    __syncthreads();
    redS[r * 8 + f4] = acc;
    __syncthreads();
    if (r == 0) {
        float4 s = make_float4(0.f, 0.f, 0.f, 0.f);
#pragma unroll
        for (int r2 = 0; r2 < 32; ++r2) {
            float4 v = redS[r2 * 8 + f4];
            s.x += v.x; s.y += v.y; s.z += v.z; s.w += v.w;
        }
        float inv = 1.f / fmaxf((float)(end - start), 1.f);
        poolS[f4 * 4 + 0] = s.x * inv;
        poolS[f4 * 4 + 1] = s.y * inv;
        poolS[f4 * 4 + 2] = s.z * inv;
        poolS[f4 * 4 + 3] = s.w * inv;
    }
    __syncthreads();
    if (tid == 0) {
        float c0 = P.blin[0], c1 = P.blin[1];
        for (int k = 0; k < 32; ++k) {
            float pk = poolS[k];
            c0 += pk * P.Wlin[k * 2 + 0];
            c1 += pk * P.Wlin[k * 2 + 1];
        }
        float m = fmaxf(c0, c1);
        float lse = m + logf(expf(c0 - m) + expf(c1 - m));
        P.out[g * 2 + 0] = c0 - lse;
        P.out[g * 2 + 1] = c1 - lse;
    }
}

// =============== cooperative single-kernel ===============
__global__ __launch_bounds__(NT, 4) void gcn_all(Params P) {
    cg::grid_group grid = cg::this_grid();
    __shared__ __align__(16) char sm[4608];
    int*    scanS = (int*)sm;
    float4* xsS   = (float4*)sm;
    float4* redS  = (float4*)sm;
    float*  poolS = (float*)(sm + 4096);

    int tid = threadIdx.x, bid = blockIdx.x, nb = gridDim.x;
    int gtid = bid * NT + tid, gs = nb * NT;

    ph_prep(P, gtid, gs);                                   grid.sync();
    ph_count(P, gtid, gs);                                  grid.sync();
    ph_scanA(P, bid, nb, tid, scanS);                       grid.sync();
    ph_scanB(P, bid, tid, scanS);                           grid.sync();
    ph_rowptr(P, gtid, gs);                                 grid.sync();
    ph_fill(P, gtid, gs);
    ph_gemm1(P, bid, nb, tid);                              grid.sync();
    ph_agg((const float4*)P.yrA, (const float4*)P.ylA, P.row_ptr, P.colIdx,
           P.b1, (float4*)P.hA, P.N, bid, nb, tid);         grid.sync();
    ph_gemm32(P.hA, P.W2r, P.W2l, P.yrB, P.ylB, P.N, bid, nb, tid, xsS);  grid.sync();
    ph_agg((const float4*)P.yrB, (const float4*)P.ylB, P.row_ptr, P.colIdx,
           P.b2, (float4*)P.hA, P.N, bid, nb, tid);         grid.sync();
    ph_gemm32(P.hA, P.W3r, P.W3l, P.yrA, P.ylA, P.N, bid, nb, tid, xsS);  grid.sync();
    ph_agg((const float4*)P.yrA, (const float4*)P.ylA, P.row_ptr, P.colIdx,
           P.b3, (float4*)P.hA, P.N, bid, nb, tid);         grid.sync();
    ph_pool(P, bid, tid, redS, poolS);
}

// =============== fallback wrappers (ordinary launches) ===============
__global__ __launch_bounds__(NT) void g_prep(Params P)   { ph_prep(P, blockIdx.x * NT + threadIdx.x, gridDim.x * NT); }
__global__ __launch_bounds__(NT) void g_count(Params P)  { ph_count(P, blockIdx.x * NT + threadIdx.x, gridDim.x * NT); }
__global__ __launch_bounds__(NT) void g_scanA(Params P)  { __shared__ int s[NT]; ph_scanA(P, blockIdx.x, gridDim.x, threadIdx.x, s); }
__global__ __launch_bounds__(NT) void g_scanB(Params P)  { __shared__ int s[NT]; ph_scanB(P, blockIdx.x, threadIdx.x, s); }
__global__ __launch_bounds__(NT) void g_rowptr(Params P) { ph_rowptr(P, blockIdx.x * NT + threadIdx.x, gridDim.x * NT); }
__global__ __launch_bounds__(NT) void g_fill(Params P)   { ph_fill(P, blockIdx.x * NT + threadIdx.x, gridDim.x * NT); }
__global__ __launch_bounds__(NT) void g_gemm1(Params P)  { ph_gemm1(P, blockIdx.x, gridDim.x, threadIdx.x); }
__global__ __launch_bounds__(NT) void g_agg(Params P, const float* yr, const float* yl,
                                            const float* b, float* h) {
    ph_agg((const float4*)yr, (const float4*)yl, P.row_ptr, P.colIdx, b, (float4*)h,
           P.N, blockIdx.x, gridDim.x, threadIdx.x);
}
__global__ __launch_bounds__(NT) void g_gemm32(Params P, const float* X, const float* Wr,
                                               const float* Wl, float* yr, float* yl) {
    __shared__ float4 xs[NT];
    ph_gemm32(X, Wr, Wl, yr, yl, P.N, blockIdx.x, gridDim.x, threadIdx.x, xs);
}
__global__ __launch_bounds__(NT) void g_pool(Params P) {
    __shared__ float4 red[256];
    __shared__ float pl[32];
    ph_pool(P, blockIdx.x, threadIdx.x, red, pl);
}

extern "C" void kernel_launch(void* const* d_in, const int* in_sizes, int n_in,
                              void* d_out, int out_size, void* d_ws, size_t ws_size,
                              hipStream_t stream) {
    Params P;
    P.x     = (const float*)d_in[0];
    const int* eidx = (const int*)d_in[1];
    P.batch = (const int*)d_in[3];
    P.W1r = (const float*)d_in[4];
    P.W1l = (const float*)d_in[5];
    P.b1  = (const float*)d_in[6];
    P.W2r = (const float*)d_in[7];
    P.W2l = (const float*)d_in[8];
    P.b2  = (const float*)d_in[9];
    P.W3r = (const float*)d_in[10];
    P.W3l = (const float*)d_in[11];
    P.b3  = (const float*)d_in[12];
    P.Wlin = (const float*)d_in[13];
    P.blin = (const float*)d_in[14];
    P.out  = (float*)d_out;

    P.N = in_sizes[0] / D_IN;   // 50000
    P.E = in_sizes[1] / 2;      // 400000
    P.src = eidx;
    P.dst = eidx + P.E;

    char* w = (char*)d_ws;
    auto alloc = [&](size_t bytes) -> void* {
        void* p = (void*)w;
        w += (bytes + 255) & ~(size_t)255;
        return p;
    };
    P.cnt     = (int*)alloc((size_t)P.N * 4);
    P.row_ptr = (int*)alloc((size_t)(P.N + 1) * 4);
    P.cursor  = (int*)alloc((size_t)(P.N + 1) * 4);
    P.colIdx  = (int*)alloc((size_t)P.E * 4);
    P.partial = (int*)alloc((size_t)256 * 4);
    P.excl    = (int*)alloc((size_t)P.N * 4);
    P.Wt      = (__hip_bfloat16*)alloc((size_t)WT_ELEMS * 2);
    P.yrA     = (float*)alloc((size_t)P.N * 32 * 4);
    P.ylA     = (float*)alloc((size_t)P.N * 32 * 4);
    P.yrB     = (float*)alloc((size_t)P.N * 32 * 4);
    P.ylB     = (float*)alloc((size_t)P.N * 32 * 4);
    P.hA      = (float*)alloc((size_t)P.N * 32 * 4);

    // grid size from actual occupancy (cooperative launch requires
    // grid <= maxActiveBlocksPerCU * numCUs); MI355X has 256 CUs.
    int maxB = 0;
    hipError_t qerr = hipOccupancyMaxActiveBlocksPerMultiprocessor(&maxB, gcn_all, NT, 0);
    int nb = (qerr == hipSuccess && maxB >= 1) ? maxB * 256 : 512;
    if (nb > 1024) nb = 1024;
    if (nb < 256) nb = 256;   // phases need >=196 blocks (scan) and >=64 (pool)

    void* args[] = { (void*)&P };
    hipError_t err = hipLaunchCooperativeKernel((const void*)gcn_all, dim3(nb), dim3(NT),
                                                args, 0, stream);
    if (err != hipSuccess) {
        // fallback: same phases as 12 ordinary (graph-capturable) launches
        int egrid  = (P.E + NT - 1) / NT;            // 1563
        int pgrid  = (P.N + WT_ELEMS + NT - 1) / NT; // 254
        int ngrid  = (P.N + NT - 1) / NT;            // 196
        int t64    = (P.N + 63) / 64;                // 782
        int t32    = (P.N + 31) / 32;                // 1563
        g_prep<<<pgrid, NT, 0, stream>>>(P);
        g_count<<<egrid, NT, 0, stream>>>(P);
        g_scanA<<<NSCB, NT, 0, stream>>>(P);
        g_scanB<<<1, NT, 0, stream>>>(P);
        g_rowptr<<<ngrid, NT, 0, stream>>>(P);
        g_fill<<<egrid, NT, 0, stream>>>(P);
        g_gemm1<<<t64, NT, 0, stream>>>(P);
        g_agg<<<t32, NT, 0, stream>>>(P, P.yrA, P.ylA, P.b1, P.hA);
        g_gemm32<<<t32, NT, 0, stream>>>(P, P.hA, P.W2r, P.W2l, P.yrB, P.ylB);
        g_agg<<<t32, NT, 0, stream>>>(P, P.yrB, P.ylB, P.b2, P.hA);
        g_gemm32<<<t32, NT, 0, stream>>>(P, P.hA, P.W3r, P.W3l, P.yrA, P.ylA);
        g_agg<<<t32, NT, 0, stream>>>(P, P.yrA, P.ylA, P.b3, P.hA);
        g_pool<<<N_GRAPHS, NT, 0, stream>>>(P);
    }
}

// Round 10
// 233.804 us; speedup vs baseline: 4.3255x; 4.3255x over previous
//
#include <hip/hip_runtime.h>
#include <hip/hip_bf16.h>

// GCN: 3x GraphConv(sum-agg) + ELU, mean-pool, linear head, log_softmax.
// N=50000, E=400000, G=64, D_IN=200, D_HID=32. fp32 inputs/outputs.
// R10: back to multi-kernel (R9 proved grid.sync() costs ~120us each on
// MI355X -- coop single-kernel was 6x slower). vs R7: (1) gathered y_r rows
// stored bf16 (64B/edge instead of 128B; L2-friendlier), (2) scan collapsed
// to ONE lookback kernel (196 co-resident blocks spin on published partials),
// (3) fill_csr fused with MFMA gemm1. 10 dispatches total.

#define D_IN 200
#define N_GRAPHS 64

#define KP 232                 // padded K stride for bf16 Wt
#define KB 7                   // 7 k-blocks of 32
#define WT_ELEMS (64 * KP)     // 14848

#define NT 256
#define NSCB 196               // scan tiles: 196*256 = 50176 >= N

typedef __attribute__((ext_vector_type(8))) short bf16x8;
typedef __attribute__((ext_vector_type(4))) float f32x4;

__device__ __forceinline__ float4 elu4(float4 v) {
    float4 o;
    o.x = (v.x > 0.f) ? v.x : expm1f(v.x);
    o.y = (v.y > 0.f) ? v.y : expm1f(v.y);
    o.z = (v.z > 0.f) ? v.z : expm1f(v.z);
    o.w = (v.w > 0.f) ? v.w : expm1f(v.w);
    return o;
}

// ---------------- count in-degrees + pack [W1r|W1l] -> bf16 Wt ----------------
__global__ __launch_bounds__(NT) void count_pack(const int* __restrict__ dst,
                                                 int* __restrict__ cnt, int E,
                                                 const float* __restrict__ Wr,
                                                 const float* __restrict__ Wl,
                                                 __hip_bfloat16* __restrict__ Wt, int egrid) {
    int blk = blockIdx.x;
    if (blk < egrid) {
        int e = blk * NT + threadIdx.x;
        if (e < E) atomicAdd(&cnt[dst[e]], 1);
    } else {
        int idx = (blk - egrid) * NT + threadIdx.x;
        if (idx < WT_ELEMS) {
            int n = idx / KP, k = idx % KP;
            float v = 0.f;
            if (k < D_IN) v = (n < 32) ? Wr[k * 32 + n] : Wl[k * 32 + (n - 32)];
            Wt[idx] = __float2bfloat16(v);
        }
    }
}

// ---------------- single-kernel scan w/ lookback (196 co-resident blocks) ----
// Each tile: local scan, publish inclusive total (release), spin for all
// predecessors' totals (acquire), sum -> offset, write row_ptr/cursor.
__global__ __launch_bounds__(NT) void scan_fused(const int* __restrict__ cnt,
                                                 int* __restrict__ row_ptr,
                                                 int* __restrict__ cursor,
                                                 int* __restrict__ partialSum,
                                                 int* __restrict__ flag, int N) {
    __shared__ int s[NT];
    int tile = blockIdx.x, tid = threadIdx.x;
    int idx = tile * NT + tid;
    int v = (idx < N) ? cnt[idx] : 0;
    s[tid] = v;
    __syncthreads();
    for (int off = 1; off < NT; off <<= 1) {
        int u = (tid >= off) ? s[tid - off] : 0;
        __syncthreads();
        s[tid] += u;
        __syncthreads();
    }
    int excl = s[tid] - v;
    int total = s[NT - 1];
    if (tid == 0) {
        __hip_atomic_store(&partialSum[tile], total, __ATOMIC_RELAXED, __HIP_MEMORY_SCOPE_AGENT);
        __hip_atomic_store(&flag[tile], 1, __ATOMIC_RELEASE, __HIP_MEMORY_SCOPE_AGENT);
    }
    int ps = 0;
    if (tid < tile) {   // tile <= 195 < NT: one predecessor per thread
        while (__hip_atomic_load(&flag[tid], __ATOMIC_ACQUIRE, __HIP_MEMORY_SCOPE_AGENT) == 0) {}
        ps = __hip_atomic_load(&partialSum[tid], __ATOMIC_RELAXED, __HIP_MEMORY_SCOPE_AGENT);
    }
    __syncthreads();
    s[tid] = ps;
    __syncthreads();
    for (int off = 128; off > 0; off >>= 1) {
        if (tid < off) s[tid] += s[tid + off];
        __syncthreads();
    }
    int rp = s[0] + excl;
    if (idx < N) { row_ptr[idx] = rp; cursor[idx] = rp; }
    if (idx == N - 1) row_ptr[N] = rp + v;
}

// ---------------- fill CSR + layer-1 MFMA gemm (fused, independent) ----------
// gemm: LDS-free (R7). A-frags straight from global fp32 (cvt in-register),
// B-frags from L2-hot packed Wt. Epilogue: cols 0..31 -> yr as bf16 row
// (node*32 elems of 2B), cols 32..63 -> yl fp32.
__global__ __launch_bounds__(NT) void fill_gemm1(const int* __restrict__ src,
                                                 const int* __restrict__ dst,
                                                 int* __restrict__ cursor,
                                                 int* __restrict__ colIdx, int E,
                                                 const float* __restrict__ X,
                                                 const __hip_bfloat16* __restrict__ Wt,
                                                 __hip_bfloat16* __restrict__ yr16,
                                                 float* __restrict__ yl, int N) {
    int tid = threadIdx.x, bid = blockIdx.x, nb = gridDim.x;
    for (int e = bid * NT + tid; e < E; e += nb * NT) {
        int p = atomicAdd(&cursor[dst[e]], 1);
        colIdx[p] = src[e];
    }
    int lane = tid & 63, wv = tid >> 6;
    int l15 = lane & 15, q = lane >> 4;
    int ntile = (N + 63) >> 6;
    for (int tile = bid; tile < ntile; tile += nb) {
        long base = (long)tile * 64;
        long row = base + wv * 16 + l15;
        long rowc = (row < (long)N) ? row : (long)(N - 1);
        const float* xr = X + rowc * D_IN;
        bf16x8 a[KB];
#pragma unroll
        for (int kb = 0; kb < KB; ++kb) {
            int k0 = kb * 32 + q * 8;
            union { __hip_bfloat16 h[8]; bf16x8 v; } u;
            if (k0 + 8 <= D_IN) {
                float4 v0 = *(const float4*)(xr + k0);
                float4 v1 = *(const float4*)(xr + k0 + 4);
                u.h[0] = __float2bfloat16(v0.x); u.h[1] = __float2bfloat16(v0.y);
                u.h[2] = __float2bfloat16(v0.z); u.h[3] = __float2bfloat16(v0.w);
                u.h[4] = __float2bfloat16(v1.x); u.h[5] = __float2bfloat16(v1.y);
                u.h[6] = __float2bfloat16(v1.z); u.h[7] = __float2bfloat16(v1.w);
            } else {
#pragma unroll
                for (int j = 0; j < 8; ++j) {
                    int k = k0 + j;
                    u.h[j] = __float2bfloat16(k < D_IN ? xr[k] : 0.f);
                }
            }
            a[kb] = u.v;
        }
#pragma unroll
        for (int ns = 0; ns < 4; ++ns) {
            f32x4 acc = {0.f, 0.f, 0.f, 0.f};
#pragma unroll
            for (int kb = 0; kb < KB; ++kb) {
                bf16x8 bfrag = *(const bf16x8*)(const void*)
                    (Wt + (ns * 16 + l15) * KP + kb * 32 + q * 8);
                acc = __builtin_amdgcn_mfma_f32_16x16x32_bf16(a[kb], bfrag, acc, 0, 0, 0);
            }
            int col = ns * 16 + l15;
#pragma unroll
            for (int r = 0; r < 4; ++r) {
                long node = base + wv * 16 + q * 4 + r;
                if (node < N) {
                    if (col < 32) yr16[node * 32 + col] = __float2bfloat16(acc[r]);
                    else          yl[node * 32 + (col - 32)] = acc[r];
                }
            }
        }
    }
}

// ---------------- aggregate (CSR pull of bf16 rows) + bias + root + ELU ------
// 4 lanes/node (each 16B = 8 bf16 feats), 64 nodes/block. Unroll-8 masked.
__global__ __launch_bounds__(NT) void agg_elu_k(const __hip_bfloat16* __restrict__ yr16,
                                                const float* __restrict__ yl,
                                                const int* __restrict__ row_ptr,
                                                const int* __restrict__ colIdx,
                                                const float* __restrict__ b,
                                                float* __restrict__ hout, int N) {
    int tid = threadIdx.x;
    int ln = tid & 3;                       // 16B chunk within 64B row
    int node = blockIdx.x * 64 + (tid >> 2);
    if (node >= N) return;
    const uint4* yv = (const uint4*)yr16;   // row = 4 x uint4
    int s = row_ptr[node], e = row_ptr[node + 1];
    int f0 = ln * 8;
    float4 bA = *(const float4*)(b + f0);
    float4 bB = *(const float4*)(b + f0 + 4);
    float4 rA = *(const float4*)(yl + (long)node * 32 + f0);
    float4 rB = *(const float4*)(yl + (long)node * 32 + f0 + 4);
    float acc[8] = {0.f, 0.f, 0.f, 0.f, 0.f, 0.f, 0.f, 0.f};
    for (int p = s; p < e; p += 8) {
        int jj[8]; float m[8];
#pragma unroll
        for (int i = 0; i < 8; ++i) {
            int pi = p + i;
            m[i] = (pi < e) ? 1.f : 0.f;
            pi = (pi < e) ? pi : (e - 1);
            jj[i] = colIdx[pi];
        }
        uint4 v[8];
#pragma unroll
        for (int i = 0; i < 8; ++i) v[i] = yv[(long)jj[i] * 4 + ln];
#pragma unroll
        for (int i = 0; i < 8; ++i) {
            uint d0 = v[i].x, d1 = v[i].y, d2 = v[i].z, d3 = v[i].w;
            acc[0] = fmaf(__uint_as_float(d0 << 16),          m[i], acc[0]);
            acc[1] = fmaf(__uint_as_float(d0 & 0xffff0000u),  m[i], acc[1]);
            acc[2] = fmaf(__uint_as_float(d1 << 16),          m[i], acc[2]);
            acc[3] = fmaf(__uint_as_float(d1 & 0xffff0000u),  m[i], acc[3]);
            acc[4] = fmaf(__uint_as_float(d2 << 16),          m[i], acc[4]);
            acc[5] = fmaf(__uint_as_float(d2 & 0xffff0000u),  m[i], acc[5]);
            acc[6] = fmaf(__uint_as_float(d3 << 16),          m[i], acc[6]);
            acc[7] = fmaf(__uint_as_float(d3 & 0xffff0000u),  m[i], acc[7]);
        }
    }
    float4 oA = elu4(make_float4(acc[0] + bA.x + rA.x, acc[1] + bA.y + rA.y,
                                 acc[2] + bA.z + rA.z, acc[3] + bA.w + rA.w));
    float4 oB = elu4(make_float4(acc[4] + bB.x + rB.x, acc[5] + bB.y + rB.y,
                                 acc[6] + bB.z + rB.z, acc[7] + bB.w + rB.w));
    *(float4*)(hout + (long)node * 32 + f0) = oA;
    *(float4*)(hout + (long)node * 32 + f0 + 4) = oB;
}

// ---------------- fp32 K=32 gemm (layers 2,3); yr written bf16 ----------------
__global__ __launch_bounds__(NT) void gemm_xw(const float* __restrict__ X,
                                              const float* __restrict__ Wr,
                                              const float* __restrict__ Wl,
                                              __hip_bfloat16* __restrict__ yr16,
                                              float* __restrict__ yl, int N) {
    __shared__ float4 xs[32 * 8];
    int t = threadIdx.x;
    long base = (long)blockIdx.x * 32;
    const float4* X4 = (const float4*)X;
    long total4 = (long)N * 8;
    long g0 = base * 8;
    for (int i = t; i < 32 * 8; i += NT) {
        long gi = g0 + i;
        xs[i] = (gi < total4) ? X4[gi] : make_float4(0.f, 0.f, 0.f, 0.f);
    }
    __syncthreads();

    int c = t & 31;
    int nb2 = (t >> 5) * 4;
    float accr[4] = {0.f, 0.f, 0.f, 0.f};
    float accl[4] = {0.f, 0.f, 0.f, 0.f};
    for (int k4 = 0; k4 < 8; ++k4) {
        float wr[4], wl[4];
#pragma unroll
        for (int qq = 0; qq < 4; ++qq) {
            wr[qq] = Wr[(k4 * 4 + qq) * 32 + c];
            wl[qq] = Wl[(k4 * 4 + qq) * 32 + c];
        }
#pragma unroll
        for (int i = 0; i < 4; ++i) {
            float4 xv = xs[(nb2 + i) * 8 + k4];
            accr[i] = fmaf(xv.x, wr[0], accr[i]); accr[i] = fmaf(xv.y, wr[1], accr[i]);
            accr[i] = fmaf(xv.z, wr[2], accr[i]); accr[i] = fmaf(xv.w, wr[3], accr[i]);
            accl[i] = fmaf(xv.x, wl[0], accl[i]); accl[i] = fmaf(xv.y, wl[1], accl[i]);
            accl[i] = fmaf(xv.z, wl[2], accl[i]); accl[i] = fmaf(xv.w, wl[3], accl[i]);
        }
    }
#pragma unroll
    for (int i = 0; i < 4; ++i) {
        long node = base + nb2 + i;
        if (node < N) {
            yr16[node * 32 + c] = __float2bfloat16(accr[i]);
            yl[node * 32 + c] = accl[i];
        }
    }
}

// ---------------- mean pool + linear head + log_softmax ----------------
__global__ __launch_bounds__(NT) void pool_head(const float4* __restrict__ h4,
                                                const int* __restrict__ batch,
                                                const float* __restrict__ Wlin,
                                                const float* __restrict__ blin,
                                                float* __restrict__ out, int N) {
    int g = blockIdx.x;
    int lo = 0, hi = N;
    while (lo < hi) { int mid = (lo + hi) >> 1; if (batch[mid] < g) lo = mid + 1; else hi = mid; }
    int start = lo;
    hi = N;
    while (lo < hi) { int mid = (lo + hi) >> 1; if (batch[mid] < g + 1) lo = mid + 1; else hi = mid; }
    int end = lo;

    int f4 = threadIdx.x & 7, r = threadIdx.x >> 3;
    float4 acc = make_float4(0.f, 0.f, 0.f, 0.f);
    for (int i = start + r; i < end; i += 32) {
        float4 v = h4[(long)i * 8 + f4];
        acc.x += v.x; acc.y += v.y; acc.z += v.z; acc.w += v.w;
    }
    __shared__ float4 red[32][8];
    __shared__ float pooledS[32];
    red[r][f4] = acc;
    __syncthreads();
    if (r == 0) {
        float4 s = make_float4(0.f, 0.f, 0.f, 0.f);
#pragma unroll
        for (int r2 = 0; r2 < 32; ++r2) {
            float4 v = red[r2][f4];
            s.x += v.x; s.y += v.y; s.z += v.z; s.w += v.w;
        }
        float inv = 1.f / fmaxf((float)(end - start), 1.f);
        pooledS[f4 * 4 + 0] = s.x * inv;
        pooledS[f4 * 4 + 1] = s.y * inv;
        pooledS[f4 * 4 + 2] = s.z * inv;
        pooledS[f4 * 4 + 3] = s.w * inv;
    }
    __syncthreads();
    if (threadIdx.x == 0) {
        float c0 = blin[0], c1 = blin[1];
        for (int k = 0; k < 32; ++k) {
            float pk = pooledS[k];
            c0 += pk * Wlin[k * 2 + 0];
            c1 += pk * Wlin[k * 2 + 1];
        }
        float m = fmaxf(c0, c1);
        float lse = m + logf(expf(c0 - m) + expf(c1 - m));
        out[g * 2 + 0] = c0 - lse;
        out[g * 2 + 1] = c1 - lse;
    }
}

extern "C" void kernel_launch(void* const* d_in, const int* in_sizes, int n_in,
                              void* d_out, int out_size, void* d_ws, size_t ws_size,
                              hipStream_t stream) {
    const float* x     = (const float*)d_in[0];
    const int*   eidx  = (const int*)d_in[1];
    const int*   batch = (const int*)d_in[3];
    const float* W1r = (const float*)d_in[4];
    const float* W1l = (const float*)d_in[5];
    const float* b1  = (const float*)d_in[6];
    const float* W2r = (const float*)d_in[7];
    const float* W2l = (const float*)d_in[8];
    const float* b2  = (const float*)d_in[9];
    const float* W3r = (const float*)d_in[10];
    const float* W3l = (const float*)d_in[11];
    const float* b3  = (const float*)d_in[12];
    const float* Wlin = (const float*)d_in[13];
    const float* blin = (const float*)d_in[14];
    float* out = (float*)d_out;

    const int N = in_sizes[0] / D_IN;  // 50000
    const int E = in_sizes[1] / 2;     // 400000
    const int* src = eidx;
    const int* dst = eidx + E;

    char* w = (char*)d_ws;
    auto alloc = [&](size_t bytes) -> void* {
        void* p = (void*)w;
        w += (bytes + 255) & ~(size_t)255;
        return p;
    };
    int* cnt     = (int*)alloc((size_t)N * 4);
    int* flag    = (int*)alloc((size_t)256 * 4);        // adjacent to cnt: one memset
    int* row_ptr = (int*)alloc((size_t)(N + 1) * 4);
    int* cursor  = (int*)alloc((size_t)(N + 1) * 4);
    int* colIdx  = (int*)alloc((size_t)E * 4);
    int* partial = (int*)alloc((size_t)256 * 4);
    __hip_bfloat16* Wt    = (__hip_bfloat16*)alloc((size_t)WT_ELEMS * 2);
    __hip_bfloat16* yr16A = (__hip_bfloat16*)alloc((size_t)N * 32 * 2);
    __hip_bfloat16* yr16B = (__hip_bfloat16*)alloc((size_t)N * 32 * 2);
    float* ylA = (float*)alloc((size_t)N * 32 * 4);
    float* ylB = (float*)alloc((size_t)N * 32 * 4);
    float* hA  = (float*)alloc((size_t)N * 32 * 4);

    // zero cnt + flag in one memset (they are adjacent allocations)
    size_t zlen = (size_t)((char*)partial - (char*)cnt) - ((size_t)(N + 1) * 4 + 255 & ~(size_t)255);
    (void)zlen;  // simpler: zero cnt..flag explicitly
    hipMemsetAsync(cnt, 0, ((size_t)N * 4 + 255 & ~(size_t)255) + 1024, stream);

    int egrid = (E + NT - 1) / NT;           // 1563
    int wgrid = (WT_ELEMS + NT - 1) / NT;    // 58
    int t64   = (N + 63) / 64;               // 782
    int t32   = (N + 31) / 32;               // 1563

    count_pack<<<egrid + wgrid, NT, 0, stream>>>(dst, cnt, E, W1r, W1l, Wt, egrid);
    scan_fused<<<NSCB, NT, 0, stream>>>(cnt, row_ptr, cursor, partial, flag, N);
    fill_gemm1<<<t64, NT, 0, stream>>>(src, dst, cursor, colIdx, E, x, Wt, yr16A, ylA, N);
    agg_elu_k<<<t64, NT, 0, stream>>>(yr16A, ylA, row_ptr, colIdx, b1, hA, N);
    gemm_xw<<<t32, NT, 0, stream>>>(hA, W2r, W2l, yr16B, ylB, N);
    agg_elu_k<<<t64, NT, 0, stream>>>(yr16B, ylB, row_ptr, colIdx, b2, hA, N);
    gemm_xw<<<t32, NT, 0, stream>>>(hA, W3r, W3l, yr16A, ylA, N);
    agg_elu_k<<<t64, NT, 0, stream>>>(yr16A, ylA, row_ptr, colIdx, b3, hA, N);
    pool_head<<<N_GRAPHS, NT, 0, stream>>>((const float4*)hA, batch, Wlin, blin, out, N);
}